// Round 7
// baseline (263.969 us; speedup 1.0000x reference)
//
#include <hip/hip_runtime.h>
#include <hip/hip_bf16.h>

// B=4, S=512, T=32, D_MODEL=512, N_HEAD=8, D_HEAD=64;  BS=2048.
// R7: 5 launches (k_prep deleted).
//  - gemm64x<AF32,WF32>: fp32 operands reg-staged (float4x2 -> cvt -> 16B LDS
//    write at the exact gl_lds16 address: &s[seg*2048 + tid*8]); bf16 operands
//    keep global_load_lds. LDS contents bit-identical to R6's pipeline.
//  - k_q self-converts src/Wq from fp32 and builds Tk in its tail (b<128).
//  - k_qk: LDS-bounce coalesced qkh writes (pad 132 shorts: conflict-free).
//  - k_attn unchanged (R6-verified). k_ao/k_out self-convert their fp32 W.
// Decomposition (R5/R6): harness fills ~157us fixed; our pipeline ~95us;
// tgt fp32 read (134MB ~ 21us) is the attn floor.

typedef __attribute__((ext_vector_type(8))) short frag8;   // 8 bf16
typedef __attribute__((ext_vector_type(4))) float f32x4;

__device__ __forceinline__ short f2s(float v) {
    return __builtin_bit_cast(short, __float2bfloat16(v));
}
__device__ __forceinline__ float s2f(short x) {
    return __builtin_bit_cast(float, (unsigned)(unsigned short)x << 16);
}
__device__ __forceinline__ void stv(float* p, float v)          { *p = v; }
__device__ __forceinline__ void stv(__hip_bfloat16* p, float v) { *p = __float2bfloat16(v); }

__device__ __forceinline__ void gl_lds16(const __hip_bfloat16* g, __hip_bfloat16* l) {
    __builtin_amdgcn_global_load_lds(
        (const __attribute__((address_space(1))) unsigned int*)g,
        (__attribute__((address_space(3))) unsigned int*)l, 16, 0, 0);
}

__device__ __forceinline__ frag8 cvt8(const float* p) {
    float4 u = *(const float4*)p, v = *(const float4*)(p + 4);
    frag8 o = { f2s(u.x), f2s(u.y), f2s(u.z), f2s(u.w),
                f2s(v.x), f2s(v.y), f2s(v.z), f2s(v.w) };
    return o;
}

// ---------------- 64x64-tile LDS-staged B^T GEMM, fp32/bf16 operands --------
// AF32/WF32: operand is fp32 -> reg-staged convert; else bf16 global_load_lds.
// Both paths produce identical LDS bits (XOR-swizzled layout, R5/R6-verified).
template<bool AF32, bool WF32, typename OUTT>
__device__ __forceinline__
void gemm64x(const void* Aop, const void* Wop,
             const float* __restrict__ bias, OUTT* __restrict__ C,
             const int* __restrict__ zmask,
             int N, int K, int tm, int tn, char* smem, int tid)
{
    short* sA = (short*)smem;          // 2 segs x 32 rows x 64 cols
    short* sB = sA + 4096;
    int lane = tid & 63, w = tid >> 6;
    int wm = w >> 1, wn = w & 1;
    int m = lane & 15, q = lane >> 4;
    int sw = (m & 7) * 8;                       // read-side XOR (shorts)
    int trow = tid >> 3;                        // staging row (0..31)
    int tcb  = ((tid & 7) ^ (trow & 7)) * 8;    // pre-swizzled source col-block
    int wbase = (tid & ~63) * 8;

    f32x4 acc[2][2];
#pragma unroll
    for (int i = 0; i < 2; ++i)
#pragma unroll
        for (int j = 0; j < 2; ++j) acc[i][j] = {0.f, 0.f, 0.f, 0.f};

    for (int k0 = 0; k0 < K; k0 += 64) {
        if constexpr (AF32) {
            const float* Af = (const float*)Aop + (size_t)tm * 64 * K;
#pragma unroll
            for (int s = 0; s < 2; ++s)
                *(frag8*)&sA[s * 2048 + tid * 8] =
                    cvt8(Af + (size_t)(s * 32 + trow) * K + k0 + tcb);
        } else {
            const __hip_bfloat16* Ab = (const __hip_bfloat16*)Aop + (size_t)tm * 64 * K;
            gl_lds16(Ab + (size_t)trow * K + k0 + tcb,        (__hip_bfloat16*)&sA[wbase]);
            gl_lds16(Ab + (size_t)(32 + trow) * K + k0 + tcb, (__hip_bfloat16*)&sA[2048 + wbase]);
        }
        if constexpr (WF32) {
            const float* Wf = (const float*)Wop + (size_t)tn * 64 * K;
#pragma unroll
            for (int s = 0; s < 2; ++s)
                *(frag8*)&sB[s * 2048 + tid * 8] =
                    cvt8(Wf + (size_t)(s * 32 + trow) * K + k0 + tcb);
        } else {
            const __hip_bfloat16* Wb = (const __hip_bfloat16*)Wop + (size_t)tn * 64 * K;
            gl_lds16(Wb + (size_t)trow * K + k0 + tcb,        (__hip_bfloat16*)&sB[wbase]);
            gl_lds16(Wb + (size_t)(32 + trow) * K + k0 + tcb, (__hip_bfloat16*)&sB[2048 + wbase]);
        }
        __syncthreads();
#pragma unroll
        for (int ki = 0; ki < 2; ++ki) {
            frag8 af[2], bf2[2];
#pragma unroll
            for (int i = 0; i < 2; ++i)
                af[i] = *(const frag8*)&sA[(wm * 32 + i * 16 + m) * 64 + ((ki * 32 + q * 8) ^ sw)];
#pragma unroll
            for (int j = 0; j < 2; ++j)
                bf2[j] = *(const frag8*)&sB[(wn * 32 + j * 16 + m) * 64 + ((ki * 32 + q * 8) ^ sw)];
#pragma unroll
            for (int i = 0; i < 2; ++i)
#pragma unroll
                for (int j = 0; j < 2; ++j)
                    acc[i][j] = __builtin_amdgcn_mfma_f32_16x16x32_bf16(
                        af[i], bf2[j], acc[i][j], 0, 0, 0);
        }
        __syncthreads();
    }

    int rb = q * 4;
    bool zr[2][4] = {{false,false,false,false},{false,false,false,false}};
    if (zmask) {
#pragma unroll
        for (int i = 0; i < 2; ++i)
#pragma unroll
            for (int t = 0; t < 4; ++t) {
                int row = tm * 64 + wm * 32 + i * 16 + rb + t;
                const uint4* mp = (const uint4*)(zmask + (size_t)row * 32);
                unsigned a = 0xffffffffu;
#pragma unroll
                for (int u = 0; u < 8; ++u) { uint4 v = mp[u]; a &= v.x & v.y & v.z & v.w; }
                zr[i][t] = (a != 0u);
            }
    }
#pragma unroll
    for (int j = 0; j < 2; ++j) {
        int   col = tn * 64 + wn * 32 + j * 16 + m;
        float bv  = bias[col];
#pragma unroll
        for (int i = 0; i < 2; ++i) {
            int row0 = tm * 64 + wm * 32 + i * 16 + rb;
#pragma unroll
            for (int t = 0; t < 4; ++t) {
                float v = acc[i][j][t] + bv;
                if (zr[i][t]) v = 0.f;
                stv(&C[(size_t)(row0 + t) * N + col], v);
            }
        }
    }
}

// ---------------- k_q: q = src @ Wq^T + b_q (fp32 in) ; + Tk build ----------
__global__ __launch_bounds__(256)
void k_q(const float* __restrict__ src, const float* __restrict__ ipw,
         const float* __restrict__ ipb, __hip_bfloat16* __restrict__ q_bf,
         __hip_bfloat16* __restrict__ Tk)
{
    __shared__ __align__(16) char smem[16384];
    int b = blockIdx.x, tid = threadIdx.x;
    gemm64x<true, true, __hip_bfloat16>(src, ipw, ipb, q_bf, nullptr,
                                        512, 512, b >> 3, b & 7, smem, tid);
    if (b < 128) {   // Tk[c,j] = bf16(ipw[512+j, c]) : 64x64 tile per block
        __syncthreads();
        short (*tile)[65] = (short(*)[65])smem;   // 8320 B <= 16384
        int bx = b & 15, by = b >> 4;
        const float* sp = ipw + (size_t)512 * 512;
#pragma unroll
        for (int i = 0; i < 16; ++i) {
            int idx = i * 256 + tid;
            int r = idx >> 6, c = idx & 63;
            tile[r][c] = f2s(sp[(size_t)(bx * 64 + r) * 512 + by * 64 + c]);
        }
        __syncthreads();
        short* Tks = (short*)Tk;
#pragma unroll
        for (int i = 0; i < 16; ++i) {
            int idx = i * 256 + tid;
            int rr = idx >> 6, cc = idx & 63;
            Tks[(size_t)(by * 64 + rr) * 1024 + bx * 64 + cc] = tile[cc][rr];
        }
    }
}

// ---------------- k_qk: per-head qk GEMM, LDS-bounce coalesced writes -------
// 4 wave-tiles/block share (z, tm); tn = tnb + wv. sO pad 132 shorts:
// store banks = 8*(lane>>4) + r/2 span all 32 -> conflict-free.
__global__ __launch_bounds__(256)
void k_qk(const __hip_bfloat16* __restrict__ q_bf,
          const __hip_bfloat16* __restrict__ Tk,
          __hip_bfloat16* __restrict__ qkh)
{
    __shared__ short sO[32 * 132];   // 8448 B
    int tid = threadIdx.x, wv = tid >> 6, lane = tid & 63;
    int t   = blockIdx.x * 4 + wv;
    int z   = t >> 10, loc = t & 1023;
    int tm  = loc >> 4, tn = loc & 15;
    int r   = lane & 15, kq = (lane >> 4) << 3;

    const __hip_bfloat16* Ap = q_bf + (size_t)z * 64 + (size_t)(tm * 32 + r) * 512 + kq;
    const __hip_bfloat16* Wp = Tk  + (size_t)z * 64 + (size_t)(tn * 32 + r) * 1024 + kq;

    f32x4 acc[2][2];
#pragma unroll
    for (int i = 0; i < 2; ++i)
#pragma unroll
        for (int j = 0; j < 2; ++j) acc[i][j] = {0.f, 0.f, 0.f, 0.f};

#pragma unroll
    for (int k0 = 0; k0 < 64; k0 += 32) {
        frag8 a[2], bb[2];
#pragma unroll
        for (int i = 0; i < 2; ++i) a[i]  = *(const frag8*)(Ap + (size_t)i * 16 * 512 + k0);
#pragma unroll
        for (int j = 0; j < 2; ++j) bb[j] = *(const frag8*)(Wp + (size_t)j * 16 * 1024 + k0);
#pragma unroll
        for (int i = 0; i < 2; ++i)
#pragma unroll
            for (int j = 0; j < 2; ++j)
                acc[i][j] = __builtin_amdgcn_mfma_f32_16x16x32_bf16(a[i], bb[j], acc[i][j], 0, 0, 0);
    }

    int rb = (lane >> 4) * 4;
#pragma unroll
    for (int j = 0; j < 2; ++j)
#pragma unroll
        for (int i = 0; i < 2; ++i)
#pragma unroll
            for (int tq = 0; tq < 4; ++tq)
                sO[(i * 16 + rb + tq) * 132 + wv * 32 + j * 16 + r] = f2s(acc[i][j][tq]);
    __syncthreads();

    int tb  = blockIdx.x * 4;
    int zb  = tb >> 10, locb = tb & 1023;
    int tmb = locb >> 4, tnb = locb & 15;
#pragma unroll
    for (int i = 0; i < 4; ++i) {
        int u = i * 256 + tid;           // 1024 ushort4 units (32 rows x 32)
        int lr = u >> 5, c4 = (u & 31) * 4;
        *(ushort4*)&qkh[(size_t)(tmb * 32 + lr) * 4096 + zb * 512 + tnb * 32 + c4] =
            *(const ushort4*)&sO[lr * 132 + c4];
    }
}

// ---------------- attn: score + softmax + tbar (R6-verified, unchanged) -----
__global__ __launch_bounds__(256)
void k_attn(const float* __restrict__ tgt,
            const __hip_bfloat16* __restrict__ qkh,
            const int* __restrict__ mask,
            __hip_bfloat16* __restrict__ tbar)
{
    int bs   = blockIdx.x;
    int tid  = threadIdx.x;
    int lane = tid & 63;
    int wv   = tid >> 6;
    int m    = lane & 15;
    int g4   = lane >> 4;

    __shared__ short sS[32 * 520];    // 33,280 B  (T row-major, bf16)
    __shared__ short sQK[8 * 520];    // 8,320 B   (qk rows; later sP, then sO)
    __shared__ int   sM[32];

    const float* tg = tgt + (size_t)bs * 32 * 512;
#pragma unroll
    for (int i = 0; i < 16; ++i) {
        int idx = i * 256 + tid;
        int row = idx >> 7, c4 = (idx & 127) * 4;
        float4 v = *(const float4*)(tg + (size_t)row * 512 + c4);
        ushort4 o;
        o.x = (unsigned short)f2s(v.x); o.y = (unsigned short)f2s(v.y);
        o.z = (unsigned short)f2s(v.z); o.w = (unsigned short)f2s(v.w);
        *(ushort4*)&sS[row * 520 + c4] = o;
    }
    const ushort4* qk4 = (const ushort4*)(qkh + (size_t)bs * 4096);
#pragma unroll
    for (int i = 0; i < 4; ++i) {
        int u = i * 256 + tid;
        int h = u >> 7, c4 = (u & 127) * 4;
        *(ushort4*)&sQK[h * 520 + c4] = qk4[u];
    }
    if (tid < 32) sM[tid] = mask[bs * 32 + tid];
    __syncthreads();

    int mk0 = sM[m], mk1 = sM[16 + m];
    bool allm = __all((mk0 != 0) && (mk1 != 0));

    f32x4 acc0 = {0.f,0.f,0.f,0.f}, acc1 = {0.f,0.f,0.f,0.f};
    {
        const short* qb  = &sQK[(m & 7) * 520 + g4 * 8];
        const short* t0p = &sS[m * 520 + g4 * 8];
        const short* t1p = t0p + 16 * 520;
#pragma unroll
        for (int k0 = 0; k0 < 512; k0 += 32) {
            frag8 af = *(const frag8*)(qb + k0);
            frag8 b0 = *(const frag8*)(t0p + k0);
            frag8 b1 = *(const frag8*)(t1p + k0);
            acc0 = __builtin_amdgcn_mfma_f32_16x16x32_bf16(af, b0, acc0, 0, 0, 0);
            acc1 = __builtin_amdgcn_mfma_f32_16x16x32_bf16(af, b1, acc1, 0, 0, 0);
        }
    }

    float p0v[4], p1v[4];
#pragma unroll
    for (int r = 0; r < 4; ++r) {
        float s0 = acc0[r] * 0.125f, s1 = acc1[r] * 0.125f;
        if (!allm) {
            if (mk0) s0 = -__builtin_inff();
            if (mk1) s1 = -__builtin_inff();
        }
        float mx = fmaxf(s0, s1);
#pragma unroll
        for (int off = 1; off < 16; off <<= 1) mx = fmaxf(mx, __shfl_xor(mx, off));
        float e0 = __expf(s0 - mx), e1 = __expf(s1 - mx);
        float sm = e0 + e1;
#pragma unroll
        for (int off = 1; off < 16; off <<= 1) sm += __shfl_xor(sm, off);
        float inv = 1.f / sm;
        p0v[r] = e0 * inv; p1v[r] = e1 * inv;
    }
    __syncthreads();                    // score reads of sQK done -> sP overlay

    short* sPw = sQK + wv * 512;        // per-wave: 256 hi + 256 lo
    if (g4 < 2) {
#pragma unroll
        for (int r = 0; r < 4; ++r) {
            int h = g4 * 4 + r;
            short h0 = f2s(p0v[r]), h1 = f2s(p1v[r]);
            sPw[h * 32 + m]            = h0;
            sPw[h * 32 + 16 + m]       = h1;
            sPw[256 + h * 32 + m]      = f2s(p0v[r] - s2f(h0));
            sPw[256 + h * 32 + 16 + m] = f2s(p1v[r] - s2f(h1));
        }
    }
    __syncthreads();
    frag8 paH = *(const frag8*)(sPw + (m & 7) * 32 + g4 * 8);
    frag8 paL = *(const frag8*)(sPw + 256 + (m & 7) * 32 + g4 * 8);
    __syncthreads();                    // sP in registers -> sO overlay of sQK

    short* sO = sQK;                    // 8x512 = 4096 shorts (fits 4160)
#pragma unroll
    for (int ci = 0; ci < 8; ++ci) {
        int cg = wv * 8 + ci;
        int cbase = cg * 16 + m;
        frag8 vb;
#pragma unroll
        for (int j = 0; j < 8; ++j)
            vb[j] = sS[(g4 * 8 + j) * 520 + cbase];
        f32x4 d = {0.f,0.f,0.f,0.f};
        d = __builtin_amdgcn_mfma_f32_16x16x32_bf16(paH, vb, d, 0, 0, 0);
        d = __builtin_amdgcn_mfma_f32_16x16x32_bf16(paL, vb, d, 0, 0, 0);
        if (g4 < 2) {
#pragma unroll
            for (int r = 0; r < 4; ++r)
                sO[(g4 * 4 + r) * 512 + cg * 16 + m] = f2s(d[r]);
        }
    }
    __syncthreads();

    ushort4* dst = (ushort4*)(tbar + (size_t)bs * 4096);
    const ushort4* so4 = (const ushort4*)sO;
#pragma unroll
    for (int i = 0; i < 4; ++i)
        dst[i * 256 + tid] = so4[i * 256 + tid];
}

// ---------------- k_ao: ao = tbar_h @ Wv_h^T + b_v (W from fp32) ------------
__global__ __launch_bounds__(256)
void k_ao(const __hip_bfloat16* __restrict__ tbar, const float* __restrict__ ipw,
          const float* __restrict__ ipb, __hip_bfloat16* __restrict__ ao_bf)
{
    int tid = threadIdx.x, lane = tid & 63;
    int gw = blockIdx.x * 4 + (tid >> 6);      // 1024 wave-tiles
    int z = gw >> 7, loc = gw & 127;
    int tm = loc >> 1, tn = loc & 1;
    int r = lane & 15, kq = (lane >> 4) << 3;

    const __hip_bfloat16* Ap = tbar + (size_t)z * 512 + (size_t)(tm * 32 + r) * 4096 + kq;
    const float*          Wp = ipw + (size_t)(1024 + z * 64 + tn * 32 + r) * 512 + kq;

    f32x4 acc[2][2];
#pragma unroll
    for (int i = 0; i < 2; ++i)
#pragma unroll
        for (int j = 0; j < 2; ++j) acc[i][j] = {0.f, 0.f, 0.f, 0.f};

    for (int k0 = 0; k0 < 512; k0 += 32) {
        frag8 a[2], bb[2];
#pragma unroll
        for (int i = 0; i < 2; ++i) a[i] = *(const frag8*)(Ap + (size_t)i * 16 * 4096 + k0);
#pragma unroll
        for (int j = 0; j < 2; ++j) bb[j] = cvt8(Wp + (size_t)j * 16 * 512 + k0);
#pragma unroll
        for (int i = 0; i < 2; ++i)
#pragma unroll
            for (int j = 0; j < 2; ++j)
                acc[i][j] = __builtin_amdgcn_mfma_f32_16x16x32_bf16(a[i], bb[j], acc[i][j], 0, 0, 0);
    }

    int rb = (lane >> 4) * 4;
#pragma unroll
    for (int j = 0; j < 2; ++j) {
        int   col = tn * 32 + j * 16 + r;
        float bv  = ipb[1024 + z * 64 + col];
#pragma unroll
        for (int i = 0; i < 2; ++i) {
            int row0 = tm * 32 + i * 16 + rb;
#pragma unroll
            for (int t = 0; t < 4; ++t)
                ao_bf[(size_t)(row0 + t) * 512 + z * 64 + col] =
                    __float2bfloat16(acc[i][j][t] + bv);
        }
    }
}

// ---------------- k_out: out = ao @ Wout^T + b_out (W from fp32) ------------
__global__ __launch_bounds__(256)
void k_out(const __hip_bfloat16* __restrict__ ao_bf, const float* __restrict__ opw,
           const float* __restrict__ opb, float* __restrict__ out,
           const int* __restrict__ mask)
{
    __shared__ __align__(16) char smem[16384];
    int b = blockIdx.x;
    gemm64x<false, true, float>(ao_bf, opw, opb, out, mask,
                                512, 512, b >> 3, b & 7, smem, threadIdx.x);
}

extern "C" void kernel_launch(void* const* d_in, const int* in_sizes, int n_in,
                              void* d_out, int out_size, void* d_ws, size_t ws_size,
                              hipStream_t stream)
{
    const float* src  = (const float*)d_in[0]; // (2048,512)
    const float* tgt  = (const float*)d_in[1]; // (65536,512)
    const int*   mask = (const int*)d_in[2];   // (2048,32)
    const float* ipw  = (const float*)d_in[3]; // (1536,512)
    const float* ipb  = (const float*)d_in[4]; // (1536,)
    const float* opw  = (const float*)d_in[5]; // (512,512)
    const float* opb  = (const float*)d_in[6]; // (512,)
    float*       out  = (float*)d_out;         // (2048,512)

    char* ws = (char*)d_ws;
    __hip_bfloat16* q_bf   = (__hip_bfloat16*)(ws + ((size_t)4 << 20));
    __hip_bfloat16* Tk     = (__hip_bfloat16*)(ws + ((size_t)6 << 20));
    __hip_bfloat16* qkh    = (__hip_bfloat16*)(ws + ((size_t)8 << 20));
    __hip_bfloat16* tbar   = (__hip_bfloat16*)(ws + ((size_t)24 << 20));
    __hip_bfloat16* ao_bf  = (__hip_bfloat16*)(ws + ((size_t)40 << 20));

    k_q   <<<256,  256, 0, stream>>>(src, ipw, ipb, q_bf, Tk);
    k_qk  <<<2048, 256, 0, stream>>>(q_bf, Tk, qkh);
    k_attn<<<2048, 256, 0, stream>>>(tgt, qkh, mask, tbar);
    k_ao  <<<256,  256, 0, stream>>>(tbar, ipw, ipb, ao_bf);
    k_out <<<256,  256, 0, stream>>>(ao_bf, opw, opb, out, mask);
}

// Round 8
// 251.842 us; speedup vs baseline: 1.0482x; 1.0482x over previous
//
#include <hip/hip_runtime.h>
#include <hip/hip_bf16.h>

// B=4, S=512, T=32, D_MODEL=512, N_HEAD=8, D_HEAD=64;  BS=2048.
// R8 = R6 base (6 launches, k_prep restored: R7's self-convert regressed via
// fp32 panel re-reads + lost global_load_lds) with two surgical changes:
//  1) k_attn PV de-conflict: sS row addressing SROW(t)=t*520+(t>>3)*16.
//     R6's PV column reads had bank = (4j+8cg+m/2)%32 -- the 32*g4 term
//     vanishes mod 32 => all four 16-lane groups on the same 8 banks (8-way).
//     The +16-short pad per 8-row group restores the 8*g4 term => disjoint
//     bank windows, 2 lanes/bank (free). Score/staging stay <=2-way (checked).
//  2) k_qk keeps R7's LDS-bounce coalesced writes (HW-verified in R7; its
//     mechanism -- kills ~4x write amplification on 16 MB -- is independent
//     of the regressing prep change).
// Decomposition (R5/R6): harness fills ~157us fixed; pipeline ~95us;
// tgt fp32 read (134MB ~21us) is the attn floor.

typedef __attribute__((ext_vector_type(8))) short frag8;   // 8 bf16
typedef __attribute__((ext_vector_type(4))) float f32x4;

#define SROW(t) ((t) * 520 + ((t) >> 3) * 16)   // bank-rotated sS row base

__device__ __forceinline__ short f2s(float v) {
    return __builtin_bit_cast(short, __float2bfloat16(v));
}
__device__ __forceinline__ float s2f(short x) {
    return __builtin_bit_cast(float, (unsigned)(unsigned short)x << 16);
}
__device__ __forceinline__ void stv(float* p, float v)          { *p = v; }
__device__ __forceinline__ void stv(__hip_bfloat16* p, float v) { *p = __float2bfloat16(v); }

__device__ __forceinline__ void gl_lds16(const __hip_bfloat16* g, __hip_bfloat16* l) {
    __builtin_amdgcn_global_load_lds(
        (const __attribute__((address_space(1))) unsigned int*)g,
        (__attribute__((address_space(3))) unsigned int*)l, 16, 0, 0);
}

// ---------------- prep: converts (512 blocks x 1024 f4) + Tk (b<128) --------
__global__ __launch_bounds__(256)
void k_prep(const float* __restrict__ ipw, const float* __restrict__ opw,
            const float* __restrict__ src,
            __hip_bfloat16* __restrict__ ipw_bf, __hip_bfloat16* __restrict__ opw_bf,
            __hip_bfloat16* __restrict__ src_bf, __hip_bfloat16* __restrict__ Tk)
{
    __shared__ short tile[64][65];
    int b = blockIdx.x, tid = threadIdx.x;
#pragma unroll
    for (int i = 0; i < 4; ++i) {
        int g = b * 1024 + i * 256 + tid;
        const float4* in; ushort4* o4; int off;
        if (g < 196608)      { in = (const float4*)ipw; o4 = (ushort4*)ipw_bf; off = g; }
        else if (g < 262144) { in = (const float4*)opw; o4 = (ushort4*)opw_bf; off = g - 196608; }
        else                 { in = (const float4*)src; o4 = (ushort4*)src_bf; off = g - 262144; }
        float4 v = in[off];
        ushort4 o;
        o.x = (unsigned short)f2s(v.x); o.y = (unsigned short)f2s(v.y);
        o.z = (unsigned short)f2s(v.z); o.w = (unsigned short)f2s(v.w);
        o4[off] = o;
    }
    if (b < 128) {   // 64x64 transpose tile: Tk[c,j] = bf16(ipw[512+j, c])
        int bx = b & 15, by = b >> 4;
        const float* sp = ipw + (size_t)512 * 512;
#pragma unroll
        for (int i = 0; i < 16; ++i) {
            int idx = i * 256 + tid;
            int r = idx >> 6, c = idx & 63;
            tile[r][c] = f2s(sp[(size_t)(bx * 64 + r) * 512 + by * 64 + c]);
        }
        __syncthreads();
        short* Tks = (short*)Tk;
#pragma unroll
        for (int i = 0; i < 16; ++i) {
            int idx = i * 256 + tid;
            int rr = idx >> 6, cc = idx & 63;
            Tks[(size_t)(by * 64 + rr) * 1024 + bx * 64 + cc] = tile[cc][rr];
        }
    }
}

// ---------------- 64x64-tile LDS-staged B^T GEMM (4 waves, XOR-swizzled) ----
template<typename OUTT>
__device__ __forceinline__
void gemm64_dev(const __hip_bfloat16* __restrict__ A, const __hip_bfloat16* __restrict__ W,
                const float* __restrict__ bias, OUTT* __restrict__ C,
                const int* __restrict__ zmask,
                int N, int K, int tm, int tn, char* smem, int tid)
{
    short* sA = (short*)smem;          // 64*64
    short* sB = sA + 4096;
    int lane = tid & 63, w = tid >> 6;
    int wm = w >> 1, wn = w & 1;
    const __hip_bfloat16* Ab = A + (size_t)tm * 64 * K;
    const __hip_bfloat16* Wb = W + (size_t)tn * 64 * K;

    f32x4 acc[2][2];
#pragma unroll
    for (int i = 0; i < 2; ++i)
#pragma unroll
        for (int j = 0; j < 2; ++j) acc[i][j] = {0.f, 0.f, 0.f, 0.f};

    int wbase = (tid & ~63) * 8;
    int m = lane & 15, q = lane >> 4;
    int sw = (m & 7) * 8;                       // read-side XOR (shorts)
    int trow = tid >> 3;
    int tcb  = ((tid & 7) ^ (trow & 7)) * 8;    // pre-swizzled source col-block

    for (int k0 = 0; k0 < K; k0 += 64) {
        gl_lds16(Ab + (size_t)trow * K + k0 + tcb,        (__hip_bfloat16*)&sA[wbase]);
        gl_lds16(Ab + (size_t)(32 + trow) * K + k0 + tcb, (__hip_bfloat16*)&sA[2048 + wbase]);
        gl_lds16(Wb + (size_t)trow * K + k0 + tcb,        (__hip_bfloat16*)&sB[wbase]);
        gl_lds16(Wb + (size_t)(32 + trow) * K + k0 + tcb, (__hip_bfloat16*)&sB[2048 + wbase]);
        __syncthreads();
#pragma unroll
        for (int ki = 0; ki < 2; ++ki) {
            frag8 af[2], bf2[2];
#pragma unroll
            for (int i = 0; i < 2; ++i)
                af[i] = *(const frag8*)&sA[(wm * 32 + i * 16 + m) * 64 + ((ki * 32 + q * 8) ^ sw)];
#pragma unroll
            for (int j = 0; j < 2; ++j)
                bf2[j] = *(const frag8*)&sB[(wn * 32 + j * 16 + m) * 64 + ((ki * 32 + q * 8) ^ sw)];
#pragma unroll
            for (int i = 0; i < 2; ++i)
#pragma unroll
                for (int j = 0; j < 2; ++j)
                    acc[i][j] = __builtin_amdgcn_mfma_f32_16x16x32_bf16(
                        af[i], bf2[j], acc[i][j], 0, 0, 0);
        }
        __syncthreads();
    }

    int rb = q * 4;
    bool zr[2][4] = {{false,false,false,false},{false,false,false,false}};
    if (zmask) {
#pragma unroll
        for (int i = 0; i < 2; ++i)
#pragma unroll
            for (int t = 0; t < 4; ++t) {
                int row = tm * 64 + wm * 32 + i * 16 + rb + t;
                const uint4* mp = (const uint4*)(zmask + (size_t)row * 32);
                unsigned a = 0xffffffffu;
#pragma unroll
                for (int u = 0; u < 8; ++u) { uint4 v = mp[u]; a &= v.x & v.y & v.z & v.w; }
                zr[i][t] = (a != 0u);
            }
    }
#pragma unroll
    for (int j = 0; j < 2; ++j) {
        int   col = tn * 64 + wn * 32 + j * 16 + m;
        float bv  = bias[col];
#pragma unroll
        for (int i = 0; i < 2; ++i) {
            int row0 = tm * 64 + wm * 32 + i * 16 + rb;
#pragma unroll
            for (int t = 0; t < 4; ++t) {
                float v = acc[i][j][t] + bv;
                if (zr[i][t]) v = 0.f;
                stv(&C[(size_t)(row0 + t) * N + col], v);
            }
        }
    }
}

__global__ __launch_bounds__(256)
void k_q(const __hip_bfloat16* src_bf, const __hip_bfloat16* ipw_bf,
         const float* ipb, __hip_bfloat16* q_bf)
{
    __shared__ __align__(16) char smem[16384];
    int b = blockIdx.x;
    gemm64_dev<__hip_bfloat16>(src_bf, ipw_bf, ipb, q_bf, nullptr,
                               512, 512, b >> 3, b & 7, smem, threadIdx.x);
}

// ---------------- k_qk: per-head qk GEMM, LDS-bounce coalesced writes -------
// (R7-verified body.) 4 wave-tiles/block share (z, tm); tn = tnb + wv.
__global__ __launch_bounds__(256)
void k_qk(const __hip_bfloat16* __restrict__ q_bf,
          const __hip_bfloat16* __restrict__ Tk,
          __hip_bfloat16* __restrict__ qkh)
{
    __shared__ short sO[32 * 132];   // 8448 B
    int tid = threadIdx.x, wv = tid >> 6, lane = tid & 63;
    int t   = blockIdx.x * 4 + wv;
    int z   = t >> 10, loc = t & 1023;
    int tm  = loc >> 4, tn = loc & 15;
    int r   = lane & 15, kq = (lane >> 4) << 3;

    const __hip_bfloat16* Ap = q_bf + (size_t)z * 64 + (size_t)(tm * 32 + r) * 512 + kq;
    const __hip_bfloat16* Wp = Tk  + (size_t)z * 64 + (size_t)(tn * 32 + r) * 1024 + kq;

    f32x4 acc[2][2];
#pragma unroll
    for (int i = 0; i < 2; ++i)
#pragma unroll
        for (int j = 0; j < 2; ++j) acc[i][j] = {0.f, 0.f, 0.f, 0.f};

#pragma unroll
    for (int k0 = 0; k0 < 64; k0 += 32) {
        frag8 a[2], bb[2];
#pragma unroll
        for (int i = 0; i < 2; ++i) a[i]  = *(const frag8*)(Ap + (size_t)i * 16 * 512 + k0);
#pragma unroll
        for (int j = 0; j < 2; ++j) bb[j] = *(const frag8*)(Wp + (size_t)j * 16 * 1024 + k0);
#pragma unroll
        for (int i = 0; i < 2; ++i)
#pragma unroll
            for (int j = 0; j < 2; ++j)
                acc[i][j] = __builtin_amdgcn_mfma_f32_16x16x32_bf16(a[i], bb[j], acc[i][j], 0, 0, 0);
    }

    int rb = (lane >> 4) * 4;
#pragma unroll
    for (int j = 0; j < 2; ++j)
#pragma unroll
        for (int i = 0; i < 2; ++i)
#pragma unroll
            for (int tq = 0; tq < 4; ++tq)
                sO[(i * 16 + rb + tq) * 132 + wv * 32 + j * 16 + r] = f2s(acc[i][j][tq]);
    __syncthreads();

    int tb  = blockIdx.x * 4;
    int zb  = tb >> 10, locb = tb & 1023;
    int tmb = locb >> 4, tnb = locb & 15;
#pragma unroll
    for (int i = 0; i < 4; ++i) {
        int u = i * 256 + tid;           // 1024 ushort4 units (32 rows x 32)
        int lr = u >> 5, c4 = (u & 31) * 4;
        *(ushort4*)&qkh[(size_t)(tmb * 32 + lr) * 4096 + zb * 512 + tnb * 32 + c4] =
            *(const ushort4*)&sO[lr * 132 + c4];
    }
}

// ---------------- attn: score + softmax + tbar, PV bank-rotated sS ----------
__global__ __launch_bounds__(256)
void k_attn(const float* __restrict__ tgt,
            const __hip_bfloat16* __restrict__ qkh,
            const int* __restrict__ mask,
            __hip_bfloat16* __restrict__ tbar)
{
    int bs   = blockIdx.x;
    int tid  = threadIdx.x;
    int lane = tid & 63;
    int wv   = tid >> 6;
    int m    = lane & 15;
    int g4   = lane >> 4;

    __shared__ short sS[32 * 520 + 64];   // 33,408 B (T rows, +16sh pad / 8 rows)
    __shared__ short sQK[8 * 520];        // 8,320 B  (qk rows; later sP, then sO)
    __shared__ int   sM[32];

    const float* tg = tgt + (size_t)bs * 32 * 512;
#pragma unroll
    for (int i = 0; i < 16; ++i) {
        int idx = i * 256 + tid;
        int row = idx >> 7, c4 = (idx & 127) * 4;
        float4 v = *(const float4*)(tg + (size_t)row * 512 + c4);
        ushort4 o;
        o.x = (unsigned short)f2s(v.x); o.y = (unsigned short)f2s(v.y);
        o.z = (unsigned short)f2s(v.z); o.w = (unsigned short)f2s(v.w);
        *(ushort4*)&sS[SROW(row) + c4] = o;
    }
    const ushort4* qk4 = (const ushort4*)(qkh + (size_t)bs * 4096);
#pragma unroll
    for (int i = 0; i < 4; ++i) {
        int u = i * 256 + tid;
        int h = u >> 7, c4 = (u & 127) * 4;
        *(ushort4*)&sQK[h * 520 + c4] = qk4[u];
    }
    if (tid < 32) sM[tid] = mask[bs * 32 + tid];
    __syncthreads();

    int mk0 = sM[m], mk1 = sM[16 + m];
    bool allm = __all((mk0 != 0) && (mk1 != 0));

    // ---- score: every wave computes full 16x32 S redundantly ----
    f32x4 acc0 = {0.f,0.f,0.f,0.f}, acc1 = {0.f,0.f,0.f,0.f};
    {
        const short* qb  = &sQK[(m & 7) * 520 + g4 * 8];
        const short* t0p = &sS[SROW(m) + g4 * 8];
        const short* t1p = &sS[SROW(16 + m) + g4 * 8];
#pragma unroll
        for (int k0 = 0; k0 < 512; k0 += 32) {
            frag8 af = *(const frag8*)(qb + k0);
            frag8 b0 = *(const frag8*)(t0p + k0);
            frag8 b1 = *(const frag8*)(t1p + k0);
            acc0 = __builtin_amdgcn_mfma_f32_16x16x32_bf16(af, b0, acc0, 0, 0, 0);
            acc1 = __builtin_amdgcn_mfma_f32_16x16x32_bf16(af, b1, acc1, 0, 0, 0);
        }
    }

    // ---- softmax over t per row h = g4*4+r (16-lane shfl reduce) ----
    float p0v[4], p1v[4];
#pragma unroll
    for (int r = 0; r < 4; ++r) {
        float s0 = acc0[r] * 0.125f, s1 = acc1[r] * 0.125f;
        if (!allm) {
            if (mk0) s0 = -__builtin_inff();
            if (mk1) s1 = -__builtin_inff();
        }
        float mx = fmaxf(s0, s1);
#pragma unroll
        for (int off = 1; off < 16; off <<= 1) mx = fmaxf(mx, __shfl_xor(mx, off));
        float e0 = __expf(s0 - mx), e1 = __expf(s1 - mx);
        float sm = e0 + e1;
#pragma unroll
        for (int off = 1; off < 16; off <<= 1) sm += __shfl_xor(sm, off);
        float inv = 1.f / sm;
        p0v[r] = e0 * inv; p1v[r] = e1 * inv;
    }
    __syncthreads();                    // score reads of sQK done -> sP overlay

    short* sPw = sQK + wv * 512;        // per-wave: 256 hi + 256 lo
    if (g4 < 2) {
#pragma unroll
        for (int r = 0; r < 4; ++r) {
            int h = g4 * 4 + r;
            short h0 = f2s(p0v[r]), h1 = f2s(p1v[r]);
            sPw[h * 32 + m]            = h0;
            sPw[h * 32 + 16 + m]       = h1;
            sPw[256 + h * 32 + m]      = f2s(p0v[r] - s2f(h0));
            sPw[256 + h * 32 + 16 + m] = f2s(p1v[r] - s2f(h1));
        }
    }
    __syncthreads();
    frag8 paH = *(const frag8*)(sPw + (m & 7) * 32 + g4 * 8);
    frag8 paL = *(const frag8*)(sPw + 256 + (m & 7) * 32 + g4 * 8);
    __syncthreads();                    // sP in registers -> sO overlay of sQK

    // ---- PV: B-frag = direct column reads of sS (now bank-disjoint per g4) --
    short* sO = sQK;                    // 8x512 = 4096 shorts (fits 4160)
#pragma unroll
    for (int ci = 0; ci < 8; ++ci) {
        int cg = wv * 8 + ci;
        int cbase = cg * 16 + m;
        frag8 vb;
#pragma unroll
        for (int j = 0; j < 8; ++j)
            vb[j] = sS[SROW(g4 * 8 + j) + cbase];
        f32x4 d = {0.f,0.f,0.f,0.f};
        d = __builtin_amdgcn_mfma_f32_16x16x32_bf16(paH, vb, d, 0, 0, 0);
        d = __builtin_amdgcn_mfma_f32_16x16x32_bf16(paL, vb, d, 0, 0, 0);
        if (g4 < 2) {
#pragma unroll
            for (int r = 0; r < 4; ++r)
                sO[(g4 * 4 + r) * 512 + cg * 16 + m] = f2s(d[r]);
        }
    }
    __syncthreads();

    ushort4* dst = (ushort4*)(tbar + (size_t)bs * 4096);
    const ushort4* so4 = (const ushort4*)sO;
#pragma unroll
    for (int i = 0; i < 4; ++i)
        dst[i * 256 + tid] = so4[i * 256 + tid];
}

// ---------------- 32x32 wave-tile direct-global B^T GEMM (k_ao) -------------
__global__ __launch_bounds__(256)
void k_ao(const __hip_bfloat16* __restrict__ tbar, const __hip_bfloat16* __restrict__ ipw_bf,
          const float* __restrict__ ipb, __hip_bfloat16* __restrict__ ao_bf)
{
    int tid = threadIdx.x, lane = tid & 63;
    int gw = blockIdx.x * 4 + (tid >> 6);      // 1024 wave-tiles
    int z = gw >> 7, loc = gw & 127;
    int tm = loc >> 1, tn = loc & 1;
    int r = lane & 15, kq = (lane >> 4) << 3;

    const __hip_bfloat16* Ap = tbar + (size_t)z * 512 + (size_t)(tm * 32 + r) * 4096 + kq;
    const __hip_bfloat16* Wp = ipw_bf + (size_t)(1024 + z * 64 + tn * 32 + r) * 512 + kq;

    f32x4 acc[2][2];
#pragma unroll
    for (int i = 0; i < 2; ++i)
#pragma unroll
        for (int j = 0; j < 2; ++j) acc[i][j] = {0.f, 0.f, 0.f, 0.f};

    for (int k0 = 0; k0 < 512; k0 += 32) {
        frag8 a[2], bb[2];
#pragma unroll
        for (int i = 0; i < 2; ++i) a[i]  = *(const frag8*)(Ap + (size_t)i * 16 * 4096 + k0);
#pragma unroll
        for (int j = 0; j < 2; ++j) bb[j] = *(const frag8*)(Wp + (size_t)j * 16 * 512 + k0);
#pragma unroll
        for (int i = 0; i < 2; ++i)
#pragma unroll
            for (int j = 0; j < 2; ++j)
                acc[i][j] = __builtin_amdgcn_mfma_f32_16x16x32_bf16(a[i], bb[j], acc[i][j], 0, 0, 0);
    }

    int rb = (lane >> 4) * 4;
#pragma unroll
    for (int j = 0; j < 2; ++j) {
        int   col = tn * 32 + j * 16 + r;
        float bv  = ipb[1024 + z * 64 + col];
#pragma unroll
        for (int i = 0; i < 2; ++i) {
            int row0 = tm * 32 + i * 16 + rb;
#pragma unroll
            for (int t = 0; t < 4; ++t)
                ao_bf[(size_t)(row0 + t) * 512 + z * 64 + col] =
                    __float2bfloat16(acc[i][j][t] + bv);
        }
    }
}

__global__ __launch_bounds__(256)
void k_out(const __hip_bfloat16* ao_bf, const __hip_bfloat16* opw_bf,
           const float* opb, float* out, const int* mask)
{
    __shared__ __align__(16) char smem[16384];
    int b = blockIdx.x;
    gemm64_dev<float>(ao_bf, opw_bf, opb, out, mask,
                      512, 512, b >> 3, b & 7, smem, threadIdx.x);
}

extern "C" void kernel_launch(void* const* d_in, const int* in_sizes, int n_in,
                              void* d_out, int out_size, void* d_ws, size_t ws_size,
                              hipStream_t stream)
{
    const float* src  = (const float*)d_in[0]; // (2048,512)
    const float* tgt  = (const float*)d_in[1]; // (65536,512)
    const int*   mask = (const int*)d_in[2];   // (2048,32)
    const float* ipw  = (const float*)d_in[3]; // (1536,512)
    const float* ipb  = (const float*)d_in[4]; // (1536,)
    const float* opw  = (const float*)d_in[5]; // (512,512)
    const float* opb  = (const float*)d_in[6]; // (512,)
    float*       out  = (float*)d_out;         // (2048,512)

    char* ws = (char*)d_ws;
    __hip_bfloat16* src_bf = (__hip_bfloat16*)(ws);
    __hip_bfloat16* ipw_bf = (__hip_bfloat16*)(ws + ((size_t)2 << 20));
    __hip_bfloat16* opw_bf = (__hip_bfloat16*)(ws + ((size_t)2 << 20) + 1536 * 512 * 2);
    __hip_bfloat16* q_bf   = (__hip_bfloat16*)(ws + ((size_t)4 << 20));
    __hip_bfloat16* Tk     = (__hip_bfloat16*)(ws + ((size_t)6 << 20));
    __hip_bfloat16* qkh    = (__hip_bfloat16*)(ws + ((size_t)8 << 20));
    __hip_bfloat16* tbar   = (__hip_bfloat16*)(ws + ((size_t)24 << 20));
    __hip_bfloat16* ao_bf  = (__hip_bfloat16*)(ws + ((size_t)40 << 20));

    k_prep<<<512, 256, 0, stream>>>(ipw, opw, src, ipw_bf, opw_bf, src_bf, Tk);
    k_q   <<<256, 256, 0, stream>>>(src_bf, ipw_bf, ipb, q_bf);
    k_qk  <<<2048, 256, 0, stream>>>(q_bf, Tk, qkh);
    k_attn<<<2048, 256, 0, stream>>>(tgt, qkh, mask, tbar);
    k_ao  <<<256, 256, 0, stream>>>(tbar, ipw_bf, ipb, ao_bf);
    k_out <<<256, 256, 0, stream>>>(ao_bf, opw_bf, opb, out, mask);
}